// Round 2
// 211.577 us; speedup vs baseline: 1.1692x; 1.1692x over previous
//
#include <hip/hip_runtime.h>
#include <math.h>

#define BB 64
#define SS 512
#define HH 768
#define AA1 100
#define CC1 300

typedef __bf16 bf16x8 __attribute__((ext_vector_type(8)));
typedef float f32x4 __attribute__((ext_vector_type(4)));

#ifndef __has_builtin
#define __has_builtin(x) 0
#endif
#if __has_builtin(__builtin_amdgcn_global_load_lds)
#define HAVE_GLL 1
#else
#define HAVE_GLL 0
#endif

#define AS1 __attribute__((address_space(1)))
#define AS3 __attribute__((address_space(3)))

// ---------------------------------------------------------------------------
// Prep: B image for async staging (chunk-major per 32-K tile, zero-pad j>=100)
//   w1i[((kt*4+q)*112 + j)*8 + e] = bf16(w1[(kt*32+q*8+e)*100 + j])
// ---------------------------------------------------------------------------
__global__ __launch_bounds__(256) void k_prep(const float* __restrict__ w1,
                                              __bf16* __restrict__ w1i) {
    int idx = blockIdx.x * 256 + threadIdx.x;   // 86016 = 336*256
    int j = idx % 112;
    int r = idx / 112;
    int e = r & 7, g = r >> 3;  // g = kt*4 + q
    int k = (g >> 2) * 32 + (g & 3) * 8 + e;
    float v = (j < AA1) ? w1[k * AA1 + j] : 0.f;
    w1i[((size_t)g * 112 + j) * 8 + e] = (__bf16)v;
}

// ---------------------------------------------------------------------------
// Kernel 1: token attention, bf16 MFMA 16x16x32, 128-token blocks.
// Wave w: tokens w*32..w*32+31 (2 M-tiles) x 7 N-tiles -> 14 MFMA / K-iter.
// A staged fp32 via global_load_lds w/ XOR chunk swizzle; B from k_prep image.
// ---------------------------------------------------------------------------
__global__ __launch_bounds__(256) void k_token_att(
        const float* __restrict__ hs, const __bf16* __restrict__ w1i,
        const float* __restrict__ b1, const float* __restrict__ w2,
        const float* __restrict__ b2, float* __restrict__ token_att) {
    __shared__ __attribute__((aligned(16))) float lA[4096];   // 128 tok x 32 k fp32
    __shared__ __attribute__((aligned(16))) __bf16 lB[3584];  // [q][j] chunks

    const int tid = threadIdx.x;
    const int tok0 = blockIdx.x * 128;
    const int w = tid >> 6, lane = tid & 63;
    const int q = lane >> 4, ln = lane & 15;
    const int t0 = w * 32 + ln;          // tile 2w token row
    const int t1 = t0 + 16;              // tile 2w+1 token row

    f32x4 acc0[7], acc1[7];
#pragma unroll
    for (int n = 0; n < 7; n++) {
        acc0[n] = (f32x4){0.f, 0.f, 0.f, 0.f};
        acc1[n] = (f32x4){0.f, 0.f, 0.f, 0.f};
    }

    const int p0 = (2 * q) ^ (ln & 7);
    const int p1 = (2 * q + 1) ^ (ln & 7);

    for (int kt = 0; kt < 24; kt++) {
        const int ko = kt * 32;
        // ---- A: 1024 chunks (16B): chunk i -> token i>>3, glob chunk (i&7)^(tok&7)
#pragma unroll
        for (int it = 0; it < 4; it++) {
            int i = tid + it * 256;
            int tt = i >> 3, c = (i & 7) ^ (tt & 7);
            const float* g = hs + (size_t)(tok0 + tt) * HH + ko + c * 4;
#if HAVE_GLL
            __builtin_amdgcn_global_load_lds((AS1 void*)g,
                    (AS3 void*)(lA + (it * 256 + w * 64) * 4), 16, 0, 0);
#else
            *(f32x4*)&lA[i * 4] = *(const f32x4*)g;
#endif
        }
        // ---- B: 448 chunks
        {
            const __bf16* gb0 = w1i + (size_t)kt * 3584 + (size_t)tid * 8;
#if HAVE_GLL
            __builtin_amdgcn_global_load_lds((AS1 void*)gb0,
                    (AS3 void*)(lB + (w * 64) * 8), 16, 0, 0);
            if (w < 3) {
                const __bf16* gb1 = w1i + (size_t)kt * 3584 + (size_t)(tid + 256) * 8;
                __builtin_amdgcn_global_load_lds((AS1 void*)gb1,
                        (AS3 void*)(lB + (256 + w * 64) * 8), 16, 0, 0);
            }
#else
            *(bf16x8*)&lB[(size_t)tid * 8] = *(const bf16x8*)gb0;
            if (tid < 192) {
                const __bf16* gb1 = w1i + (size_t)kt * 3584 + (size_t)(tid + 256) * 8;
                *(bf16x8*)&lB[(size_t)(tid + 256) * 8] = *(const bf16x8*)gb1;
            }
#endif
        }
        __syncthreads();
        // ---- A fragments (fp32 -> bf16)
        f32x4 a00 = *(f32x4*)&lA[(t0 * 8 + p0) * 4];
        f32x4 a01 = *(f32x4*)&lA[(t0 * 8 + p1) * 4];
        f32x4 a10 = *(f32x4*)&lA[(t1 * 8 + p0) * 4];
        f32x4 a11 = *(f32x4*)&lA[(t1 * 8 + p1) * 4];
        bf16x8 af0, af1;
#pragma unroll
        for (int e = 0; e < 4; e++) {
            af0[e] = (__bf16)a00[e]; af0[e + 4] = (__bf16)a01[e];
            af1[e] = (__bf16)a10[e]; af1[e + 4] = (__bf16)a11[e];
        }
#pragma unroll
        for (int n = 0; n < 7; n++) {
            bf16x8 bf = *(bf16x8*)&lB[((size_t)q * 112 + n * 16 + ln) * 8];
            acc0[n] = __builtin_amdgcn_mfma_f32_16x16x32_bf16(af0, bf, acc0[n], 0, 0, 0);
            acc1[n] = __builtin_amdgcn_mfma_f32_16x16x32_bf16(af1, bf, acc1[n], 0, 0, 0);
        }
        __syncthreads();
    }

    // epilogue per tile: col j = n*16+ln, token = base + q*4 + reg
    float s0 = 0.f, s1 = 0.f, s2 = 0.f, s3 = 0.f;
    float u0 = 0.f, u1 = 0.f, u2 = 0.f, u3 = 0.f;
#pragma unroll
    for (int n = 0; n < 7; n++) {
        int j = n * 16 + ln;
        if (j < AA1) {
            float bj = b1[j], wj = w2[j];
            s0 += tanhf(acc0[n][0] + bj) * wj;
            s1 += tanhf(acc0[n][1] + bj) * wj;
            s2 += tanhf(acc0[n][2] + bj) * wj;
            s3 += tanhf(acc0[n][3] + bj) * wj;
            u0 += tanhf(acc1[n][0] + bj) * wj;
            u1 += tanhf(acc1[n][1] + bj) * wj;
            u2 += tanhf(acc1[n][2] + bj) * wj;
            u3 += tanhf(acc1[n][3] + bj) * wj;
        }
    }
#pragma unroll
    for (int off = 1; off < 16; off <<= 1) {
        s0 += __shfl_xor(s0, off); s1 += __shfl_xor(s1, off);
        s2 += __shfl_xor(s2, off); s3 += __shfl_xor(s3, off);
        u0 += __shfl_xor(u0, off); u1 += __shfl_xor(u1, off);
        u2 += __shfl_xor(u2, off); u3 += __shfl_xor(u3, off);
    }
    if (ln == 0) {
        float bb = b2[0];
        int base0 = tok0 + w * 32 + q * 4;
        int base1 = base0 + 16;
        token_att[base0 + 0] = 1.f / (1.f + expf(-(s0 + bb)));
        token_att[base0 + 1] = 1.f / (1.f + expf(-(s1 + bb)));
        token_att[base0 + 2] = 1.f / (1.f + expf(-(s2 + bb)));
        token_att[base0 + 3] = 1.f / (1.f + expf(-(s3 + bb)));
        token_att[base1 + 0] = 1.f / (1.f + expf(-(u0 + bb)));
        token_att[base1 + 1] = 1.f / (1.f + expf(-(u1 + bb)));
        token_att[base1 + 2] = 1.f / (1.f + expf(-(u2 + bb)));
        token_att[base1 + 3] = 1.f / (1.f + expf(-(u3 + bb)));
    }
}

// ---------------------------------------------------------------------------
// Kernel 2: scan/segmax/mask + stats + compaction -> ws.
// ---------------------------------------------------------------------------
__global__ __launch_bounds__(512) void k_mask(
        const float* __restrict__ token_att, const float* __restrict__ labels,
        const int* __restrict__ offm, float* __restrict__ masked_out,
        float* __restrict__ cw_g, short* __restrict__ cs_g,
        int* __restrict__ nnz_g, float* __restrict__ inv_g,
        float4* __restrict__ stats_g) {
    __shared__ int smax[512];
    __shared__ int wscan[8];
    __shared__ int wscan2[8];
    __shared__ float wred[5][8];

    const int b = blockIdx.x, s = threadIdx.x;
    const int lane = s & 63, wv = s >> 6;
    const int ns = (offm[(b * SS + s) * 2] == 0) ? 1 : 0;

    int v = ns;
#pragma unroll
    for (int off = 1; off < 64; off <<= 1) {
        int o = __shfl_up(v, off);
        if (lane >= off) v += o;
    }
    if (lane == 63) wscan[wv] = v;
    smax[s] = 0;
    __syncthreads();
    int woff = 0;
    for (int i = 0; i < 8; i++) woff += (i < wv) ? wscan[i] : 0;
    const int seg = max(v + woff - 1, 0);

    const float ta = token_att[b * SS + s];
    atomicMax(&smax[seg], __float_as_int(ta));   // sigmoid > 0: int order ok
    __syncthreads();

    const float wa = ns ? __int_as_float(smax[seg]) : 0.f;
    const float lab = labels[b * SS + s];
    const float m = (lab != -1.f && ns) ? wa : 0.f;
    masked_out[b * SS + s] = m;

    const float zl = (lab != -1.f) ? lab : 0.f;
    const float tl = (m - zl) * (m - zl);
    const float ones = (m == 0.f) ? 1.f : m;

    float r0 = m, r1 = tl, r2 = m, r3 = ones, r4 = lab;
#pragma unroll
    for (int off = 32; off > 0; off >>= 1) {
        r0 += __shfl_xor(r0, off);
        r1 += __shfl_xor(r1, off);
        r2 = fmaxf(r2, __shfl_xor(r2, off));
        r3 = fminf(r3, __shfl_xor(r3, off));
        r4 = fmaxf(r4, __shfl_xor(r4, off));
    }
    if (lane == 0) {
        wred[0][wv] = r0; wred[1][wv] = r1; wred[2][wv] = r2;
        wred[3][wv] = r3; wred[4][wv] = r4;
    }

    const int nz = (m != 0.f) ? 1 : 0;
    int v2 = nz;
#pragma unroll
    for (int off = 1; off < 64; off <<= 1) {
        int o = __shfl_up(v2, off);
        if (lane >= off) v2 += o;
    }
    if (lane == 63) wscan2[wv] = v2;
    __syncthreads();

    int woff2 = 0;
    for (int i = 0; i < 8; i++) woff2 += (i < wv) ? wscan2[i] : 0;
    if (nz) {
        int pos = v2 + woff2 - 1;
        cw_g[b * SS + pos] = m;
        cs_g[b * SS + pos] = (short)s;
    }
    if (s == 0) {
        float att = 0.f, tokl = 0.f, maxm = -1e30f, minone = 1e30f, slab = -1e30f;
        int nnz = 0;
        for (int i = 0; i < 8; i++) {
            att += wred[0][i]; tokl += wred[1][i];
            maxm = fmaxf(maxm, wred[2][i]);
            minone = fminf(minone, wred[3][i]);
            slab = fmaxf(slab, wred[4][i]);
            nnz += wscan2[i];
        }
        nnz_g[b] = nnz;
        inv_g[b] = 1.f / att;
        stats_g[b] = make_float4(tokl, maxm, minone, slab);
    }
}

// ---------------------------------------------------------------------------
// Kernel 3: pooling over compacted list. grid (B, 12): block (b, h-chunk of 64)
// 256 threads = 64 h x 4 K-slots -> 3072 waves total (vs 512 before).
// Also zeroes zsum[b] (atomicAdd target of k_sent, which launches after).
// ---------------------------------------------------------------------------
__global__ __launch_bounds__(256) void k_pool(
        const float* __restrict__ hs, const float* __restrict__ cw_g,
        const short* __restrict__ cs_g, const int* __restrict__ nnz_g,
        const float* __restrict__ inv_g, float* __restrict__ pooled,
        float* __restrict__ zsum) {
    __shared__ float wl[SS];
    __shared__ short il[SS];
    __shared__ float red[256];

    const int b = blockIdx.x, hc = blockIdx.y;
    const int tid = threadIdx.x;
    const int nnz = nnz_g[b];
    if (hc == 0 && tid == 0) zsum[b] = 0.f;
    if (tid < nnz) { wl[tid] = cw_g[b * SS + tid]; il[tid] = cs_g[b * SS + tid]; }
    if (tid + 256 < nnz) {
        wl[tid + 256] = cw_g[b * SS + tid + 256];
        il[tid + 256] = cs_g[b * SS + tid + 256];
    }
    __syncthreads();

    const int h = (tid & 63) + hc * 64;
    const int slot = tid >> 6;
    const float* hsb = hs + (size_t)b * SS * HH + h;
    const int len = (nnz + 3) >> 2;
    const int i0 = slot * len;
    const int i1 = min(i0 + len, nnz);
    float a0 = 0.f, a1 = 0.f, a2 = 0.f, a3 = 0.f;
    int i = i0;
    for (; i + 4 <= i1; i += 4) {
        a0 += hsb[(size_t)il[i]     * HH] * wl[i];
        a1 += hsb[(size_t)il[i + 1] * HH] * wl[i + 1];
        a2 += hsb[(size_t)il[i + 2] * HH] * wl[i + 2];
        a3 += hsb[(size_t)il[i + 3] * HH] * wl[i + 3];
    }
    for (; i < i1; i++) a0 += hsb[(size_t)il[i] * HH] * wl[i];
    red[tid] = (a0 + a1) + (a2 + a3);
    __syncthreads();
    if (tid < 64)
        pooled[(size_t)b * HH + h] =
            (red[tid] + red[tid + 64] + red[tid + 128] + red[tid + 192]) * inv_g[b];
}

// ---------------------------------------------------------------------------
// Kernel 4: sentence MLP. grid (B, 5): block (b, 60-column chunk).
// 256 threads = 64 cols (60 active) x 4 K-quarters of 192. Per-block partial
// of sum_c tanh(z_c)*sw2_c -> one atomicAdd into zsum[b].
// ---------------------------------------------------------------------------
__global__ __launch_bounds__(256) void k_sent(
        const float* __restrict__ pooled, const float* __restrict__ sw1,
        const float* __restrict__ sb1, const float* __restrict__ sw2,
        float* __restrict__ zsum) {
    __shared__ float pl[HH];
    __shared__ float red[256];

    const int b = blockIdx.x, cc = blockIdx.y;
    const int tid = threadIdx.x;
    pl[tid]       = pooled[(size_t)b * HH + tid];
    pl[tid + 256] = pooled[(size_t)b * HH + tid + 256];
    pl[tid + 512] = pooled[(size_t)b * HH + tid + 512];
    __syncthreads();

    const int cl = tid & 63, kq = tid >> 6;
    const int c = cc * 60 + cl;
    float z = 0.f;
    if (cl < 60) {
        const int k0 = kq * 192;
        for (int k = k0; k < k0 + 192; k += 8) {
#pragma unroll
            for (int u = 0; u < 8; u++)
                z += pl[k + u] * sw1[(size_t)(k + u) * CC1 + c];
        }
    }
    red[tid] = z;
    __syncthreads();
    if (kq == 0) {
        float zz = red[tid] + red[tid + 64] + red[tid + 128] + red[tid + 192];
        float t = 0.f;
        if (cl < 60) t = tanhf(zz + sb1[c]) * sw2[c];
#pragma unroll
        for (int off = 32; off > 0; off >>= 1) t += __shfl_xor(t, off);
        if (cl == 0) atomicAdd(&zsum[b], t);
    }
}

// ---------------------------------------------------------------------------
// Kernel 5: final sigmoid + losses. One wave, lane = batch row. No atomics.
// ---------------------------------------------------------------------------
__global__ __launch_bounds__(64) void k_losses(
        const float* __restrict__ zsum, const float* __restrict__ sb2,
        const float4* __restrict__ stats_g, float* __restrict__ sent_out,
        float* __restrict__ out) {
    const int b = threadIdx.x;   // 64 lanes
    const float sv = 1.f / (1.f + expf(-(zsum[b] + sb2[0])));
    sent_out[b] = sv;
    const float4 st = stats_g[b];           // tokl, maxm, minone, slab
    float vs = sv - st.w; vs *= vs;
    float ra = st.z * st.z;
    float rb = st.y - st.w; rb *= rb;
    float s0 = vs, s1 = st.x, s2 = ra, s3 = rb;
#pragma unroll
    for (int off = 32; off > 0; off >>= 1) {
        s0 += __shfl_xor(s0, off);
        s1 += __shfl_xor(s1, off);
        s2 += __shfl_xor(s2, off);
        s3 += __shfl_xor(s3, off);
    }
    if (b == 0) {
        out[1] = s0; out[2] = s1; out[3] = s2; out[4] = s3;
        out[0] = s0 + s1 + 0.01f * (s2 + s3);
    }
}

extern "C" void kernel_launch(void* const* d_in, const int* in_sizes, int n_in,
                              void* d_out, int out_size, void* d_ws, size_t ws_size,
                              hipStream_t stream) {
    const float* hs  = (const float*)d_in[0];
    const float* w1  = (const float*)d_in[1];
    const float* b1  = (const float*)d_in[2];
    const float* w2  = (const float*)d_in[3];
    const float* b2  = (const float*)d_in[4];
    const float* sw1 = (const float*)d_in[5];
    const float* sb1 = (const float*)d_in[6];
    const float* sw2 = (const float*)d_in[7];
    const float* sb2 = (const float*)d_in[8];
    const float* labels = (const float*)d_in[9];
    const int*   offm   = (const int*)d_in[10];

    float* out = (float*)d_out;
    float* ws  = (float*)d_ws;

    // ws layout (float units) — total footprint 125312 floats, identical to the
    // previously verified version. pooled/zsum ALIAS dead regions:
    //   token_att (ws+0, 32768 f)  : dead after k_mask
    //   w1i       (ws+32768, 43008 f): dead after k_token_att
    // pooled = ws[0 .. 49152)   (k_pool writes AFTER k_mask completes)
    // zsum   = ws[49152 .. 49216)
    float*  token_att = ws;                       // 32768
    __bf16* w1i    = (__bf16*)(ws + 32768);       // 86016 bf16 = 43008 f
    float*  cw     = ws + 32768 + 43008;          // 32768
    short*  cs     = (short*)(cw + 32768);        // 32768 shorts = 16384 f
    int*    nnz    = (int*)(cw + 32768 + 16384);  // 64
    float*  inv    = (float*)(nnz + 64);          // 64
    float4* stats  = (float4*)(inv + 64);         // 64 float4 = 256 f
    float*  pooled = ws;                          // aliases token_att (dead)
    float*  zsum   = ws + 49152;                  // aliases w1i tail (dead)

    // d_out layout: [total, sentence_loss, token_loss, reg_a, reg_b,
    //                masked(64*512), sent(64)]
    float* masked_out = out + 5;
    float* sent_out   = out + 5 + BB * SS;

    hipLaunchKernelGGL(k_prep, dim3(336), dim3(256), 0, stream, w1, w1i);
    hipLaunchKernelGGL(k_token_att, dim3(256), dim3(256), 0, stream,
                       hs, w1i, b1, w2, b2, token_att);
    hipLaunchKernelGGL(k_mask, dim3(BB), dim3(512), 0, stream,
                       token_att, labels, offm, masked_out,
                       cw, cs, nnz, inv, stats);
    hipLaunchKernelGGL(k_pool, dim3(BB, 12), dim3(256), 0, stream,
                       hs, cw, cs, nnz, inv, pooled, zsum);
    hipLaunchKernelGGL(k_sent, dim3(BB, 5), dim3(256), 0, stream,
                       pooled, sw1, sb1, sw2, zsum);
    hipLaunchKernelGGL(k_losses, dim3(1), dim3(64), 0, stream,
                       zsum, sb2, stats, sent_out, out);
}

// Round 4
// 208.984 us; speedup vs baseline: 1.1838x; 1.0124x over previous
//
#include <hip/hip_runtime.h>
#include <math.h>

#define BB 64
#define SS 512
#define HH 768
#define AA1 100
#define CC1 300

typedef __bf16 bf16x8 __attribute__((ext_vector_type(8)));
typedef float f32x4 __attribute__((ext_vector_type(4)));

#ifndef __has_builtin
#define __has_builtin(x) 0
#endif
#if __has_builtin(__builtin_amdgcn_global_load_lds)
#define HAVE_GLL 1
#else
#define HAVE_GLL 0
#endif

#define AS1 __attribute__((address_space(1)))
#define AS3 __attribute__((address_space(3)))

// ---------------------------------------------------------------------------
// Prep: B image (chunk-major per 32-K tile, zero-pad j>=100)
//   w1i[((kt*4+q)*112 + j)*8 + e] = bf16(w1[(kt*32+q*8+e)*100 + j])
// ---------------------------------------------------------------------------
__global__ __launch_bounds__(256) void k_prep(const float* __restrict__ w1,
                                              __bf16* __restrict__ w1i) {
    int idx = blockIdx.x * 256 + threadIdx.x;   // 86016 = 336*256
    int j = idx % 112;
    int r = idx / 112;
    int e = r & 7, g = r >> 3;  // g = kt*4 + q
    int k = (g >> 2) * 32 + (g & 3) * 8 + e;
    float v = (j < AA1) ? w1[k * AA1 + j] : 0.f;
    w1i[((size_t)g * 112 + j) * 8 + e] = (__bf16)v;
}

// ---------------------------------------------------------------------------
// Kernel 1 (v2): token attention, bf16 MFMA 16x16x32, barrier-free / LDS-free.
// Grid 512 x 256: wave w owns 16 tokens (1 M-tile) x 7 N-tiles.
// A loaded per-lane direct from hs (no reuse -> LDS was pure overhead);
// B loaded direct from the L2-resident w1i image (172 KB, read-only).
// No __syncthreads in the K-loop -> compiler software-pipelines freely.
// Lane (q,ln): A row = tok0+w*16+ln, k = q*8+e; B = w1[q*8+e][n*16+ln].
// ---------------------------------------------------------------------------
__global__ __launch_bounds__(256) void k_token_att(
        const float* __restrict__ hs, const __bf16* __restrict__ w1i,
        const float* __restrict__ b1, const float* __restrict__ w2,
        const float* __restrict__ b2, float* __restrict__ token_att) {
    const int tid = threadIdx.x;
    const int tok0 = blockIdx.x * 64;
    const int w = tid >> 6, lane = tid & 63;
    const int q = lane >> 4, ln = lane & 15;
    const int trow = tok0 + w * 16 + ln;     // A-fragment row for this lane

    f32x4 acc[7];
#pragma unroll
    for (int n = 0; n < 7; n++) acc[n] = (f32x4){0.f, 0.f, 0.f, 0.f};

    const float* ga = hs + (size_t)trow * HH + q * 8;
    const __bf16* gb = w1i + (size_t)(q * 112 + ln) * 8;

#pragma unroll 4
    for (int kt = 0; kt < 24; kt++) {
        // A: 8 consecutive fp32 at k = kt*32 + q*8
        f32x4 a0 = *(const f32x4*)(ga + kt * 32);
        f32x4 a1 = *(const f32x4*)(ga + kt * 32 + 4);
        bf16x8 af;
#pragma unroll
        for (int e = 0; e < 4; e++) {
            af[e] = (__bf16)a0[e];
            af[e + 4] = (__bf16)a1[e];
        }
        const __bf16* gbk = gb + (size_t)kt * 3584;
#pragma unroll
        for (int n = 0; n < 7; n++) {
            bf16x8 bf = *(const bf16x8*)(gbk + n * 128);
            acc[n] = __builtin_amdgcn_mfma_f32_16x16x32_bf16(af, bf, acc[n], 0, 0, 0);
        }
    }

    // epilogue: col j = n*16+ln, token = tok0 + w*16 + q*4 + reg
    float s0 = 0.f, s1 = 0.f, s2 = 0.f, s3 = 0.f;
#pragma unroll
    for (int n = 0; n < 7; n++) {
        int j = n * 16 + ln;
        if (j < AA1) {
            float bj = b1[j], wj = w2[j];
            s0 += tanhf(acc[n][0] + bj) * wj;
            s1 += tanhf(acc[n][1] + bj) * wj;
            s2 += tanhf(acc[n][2] + bj) * wj;
            s3 += tanhf(acc[n][3] + bj) * wj;
        }
    }
#pragma unroll
    for (int off = 1; off < 16; off <<= 1) {
        s0 += __shfl_xor(s0, off); s1 += __shfl_xor(s1, off);
        s2 += __shfl_xor(s2, off); s3 += __shfl_xor(s3, off);
    }
    if (ln == 0) {
        float bb = b2[0];
        int base = tok0 + w * 16 + q * 4;
        token_att[base + 0] = 1.f / (1.f + expf(-(s0 + bb)));
        token_att[base + 1] = 1.f / (1.f + expf(-(s1 + bb)));
        token_att[base + 2] = 1.f / (1.f + expf(-(s2 + bb)));
        token_att[base + 3] = 1.f / (1.f + expf(-(s3 + bb)));
    }
}

// ---------------------------------------------------------------------------
// Kernel 2: scan/segmax/mask + stats + compaction -> ws.
// ---------------------------------------------------------------------------
__global__ __launch_bounds__(512) void k_mask(
        const float* __restrict__ token_att, const float* __restrict__ labels,
        const int* __restrict__ offm, float* __restrict__ masked_out,
        float* __restrict__ cw_g, short* __restrict__ cs_g,
        int* __restrict__ nnz_g, float* __restrict__ inv_g,
        float4* __restrict__ stats_g) {
    __shared__ int smax[512];
    __shared__ int wscan[8];
    __shared__ int wscan2[8];
    __shared__ float wred[5][8];

    const int b = blockIdx.x, s = threadIdx.x;
    const int lane = s & 63, wv = s >> 6;
    const int ns = (offm[(b * SS + s) * 2] == 0) ? 1 : 0;

    int v = ns;
#pragma unroll
    for (int off = 1; off < 64; off <<= 1) {
        int o = __shfl_up(v, off);
        if (lane >= off) v += o;
    }
    if (lane == 63) wscan[wv] = v;
    smax[s] = 0;
    __syncthreads();
    int woff = 0;
    for (int i = 0; i < 8; i++) woff += (i < wv) ? wscan[i] : 0;
    const int seg = max(v + woff - 1, 0);

    const float ta = token_att[b * SS + s];
    atomicMax(&smax[seg], __float_as_int(ta));   // sigmoid > 0: int order ok
    __syncthreads();

    const float wa = ns ? __int_as_float(smax[seg]) : 0.f;
    const float lab = labels[b * SS + s];
    const float m = (lab != -1.f && ns) ? wa : 0.f;
    masked_out[b * SS + s] = m;

    const float zl = (lab != -1.f) ? lab : 0.f;
    const float tl = (m - zl) * (m - zl);
    const float ones = (m == 0.f) ? 1.f : m;

    float r0 = m, r1 = tl, r2 = m, r3 = ones, r4 = lab;
#pragma unroll
    for (int off = 32; off > 0; off >>= 1) {
        r0 += __shfl_xor(r0, off);
        r1 += __shfl_xor(r1, off);
        r2 = fmaxf(r2, __shfl_xor(r2, off));
        r3 = fminf(r3, __shfl_xor(r3, off));
        r4 = fmaxf(r4, __shfl_xor(r4, off));
    }
    if (lane == 0) {
        wred[0][wv] = r0; wred[1][wv] = r1; wred[2][wv] = r2;
        wred[3][wv] = r3; wred[4][wv] = r4;
    }

    const int nz = (m != 0.f) ? 1 : 0;
    int v2 = nz;
#pragma unroll
    for (int off = 1; off < 64; off <<= 1) {
        int o = __shfl_up(v2, off);
        if (lane >= off) v2 += o;
    }
    if (lane == 63) wscan2[wv] = v2;
    __syncthreads();

    int woff2 = 0;
    for (int i = 0; i < 8; i++) woff2 += (i < wv) ? wscan2[i] : 0;
    if (nz) {
        int pos = v2 + woff2 - 1;
        cw_g[b * SS + pos] = m;
        cs_g[b * SS + pos] = (short)s;
    }
    if (s == 0) {
        float att = 0.f, tokl = 0.f, maxm = -1e30f, minone = 1e30f, slab = -1e30f;
        int nnz = 0;
        for (int i = 0; i < 8; i++) {
            att += wred[0][i]; tokl += wred[1][i];
            maxm = fmaxf(maxm, wred[2][i]);
            minone = fminf(minone, wred[3][i]);
            slab = fmaxf(slab, wred[4][i]);
            nnz += wscan2[i];
        }
        nnz_g[b] = nnz;
        inv_g[b] = 1.f / att;
        stats_g[b] = make_float4(tokl, maxm, minone, slab);
    }
}

// ---------------------------------------------------------------------------
// Kernel 3: pooling over compacted list. grid (B, 12): block (b, h-chunk of 64)
// 256 threads = 64 h x 4 K-slots. Also zeroes zsum[b].
// ---------------------------------------------------------------------------
__global__ __launch_bounds__(256) void k_pool(
        const float* __restrict__ hs, const float* __restrict__ cw_g,
        const short* __restrict__ cs_g, const int* __restrict__ nnz_g,
        const float* __restrict__ inv_g, float* __restrict__ pooled,
        float* __restrict__ zsum) {
    __shared__ float wl[SS];
    __shared__ short il[SS];
    __shared__ float red[256];

    const int b = blockIdx.x, hc = blockIdx.y;
    const int tid = threadIdx.x;
    const int nnz = nnz_g[b];
    if (hc == 0 && tid == 0) zsum[b] = 0.f;
    if (tid < nnz) { wl[tid] = cw_g[b * SS + tid]; il[tid] = cs_g[b * SS + tid]; }
    if (tid + 256 < nnz) {
        wl[tid + 256] = cw_g[b * SS + tid + 256];
        il[tid + 256] = cs_g[b * SS + tid + 256];
    }
    __syncthreads();

    const int h = (tid & 63) + hc * 64;
    const int slot = tid >> 6;
    const float* hsb = hs + (size_t)b * SS * HH + h;
    const int len = (nnz + 3) >> 2;
    const int i0 = slot * len;
    const int i1 = min(i0 + len, nnz);
    float a0 = 0.f, a1 = 0.f, a2 = 0.f, a3 = 0.f;
    int i = i0;
    for (; i + 4 <= i1; i += 4) {
        a0 += hsb[(size_t)il[i]     * HH] * wl[i];
        a1 += hsb[(size_t)il[i + 1] * HH] * wl[i + 1];
        a2 += hsb[(size_t)il[i + 2] * HH] * wl[i + 2];
        a3 += hsb[(size_t)il[i + 3] * HH] * wl[i + 3];
    }
    for (; i < i1; i++) a0 += hsb[(size_t)il[i] * HH] * wl[i];
    red[tid] = (a0 + a1) + (a2 + a3);
    __syncthreads();
    if (tid < 64)
        pooled[(size_t)b * HH + h] =
            (red[tid] + red[tid + 64] + red[tid + 128] + red[tid + 192]) * inv_g[b];
}

// ---------------------------------------------------------------------------
// Kernel 4: sentence MLP. grid (B, 5): block (b, 60-column chunk).
// 256 threads = 64 cols (60 active) x 4 K-quarters of 192 -> atomicAdd zsum[b].
// ---------------------------------------------------------------------------
__global__ __launch_bounds__(256) void k_sent(
        const float* __restrict__ pooled, const float* __restrict__ sw1,
        const float* __restrict__ sb1, const float* __restrict__ sw2,
        float* __restrict__ zsum) {
    __shared__ float pl[HH];
    __shared__ float red[256];

    const int b = blockIdx.x, cc = blockIdx.y;
    const int tid = threadIdx.x;
    pl[tid]       = pooled[(size_t)b * HH + tid];
    pl[tid + 256] = pooled[(size_t)b * HH + tid + 256];
    pl[tid + 512] = pooled[(size_t)b * HH + tid + 512];
    __syncthreads();

    const int cl = tid & 63, kq = tid >> 6;
    const int c = cc * 60 + cl;
    float z = 0.f;
    if (cl < 60) {
        const int k0 = kq * 192;
        for (int k = k0; k < k0 + 192; k += 8) {
#pragma unroll
            for (int u = 0; u < 8; u++)
                z += pl[k + u] * sw1[(size_t)(k + u) * CC1 + c];
        }
    }
    red[tid] = z;
    __syncthreads();
    if (kq == 0) {
        float zz = red[tid] + red[tid + 64] + red[tid + 128] + red[tid + 192];
        float t = 0.f;
        if (cl < 60) t = tanhf(zz + sb1[c]) * sw2[c];
#pragma unroll
        for (int off = 32; off > 0; off >>= 1) t += __shfl_xor(t, off);
        if (cl == 0) atomicAdd(&zsum[b], t);
    }
}

// ---------------------------------------------------------------------------
// Kernel 5: final sigmoid + losses. One wave, lane = batch row. No atomics.
// ---------------------------------------------------------------------------
__global__ __launch_bounds__(64) void k_losses(
        const float* __restrict__ zsum, const float* __restrict__ sb2,
        const float4* __restrict__ stats_g, float* __restrict__ sent_out,
        float* __restrict__ out) {
    const int b = threadIdx.x;   // 64 lanes
    const float sv = 1.f / (1.f + expf(-(zsum[b] + sb2[0])));
    sent_out[b] = sv;
    const float4 st = stats_g[b];           // tokl, maxm, minone, slab
    float vs = sv - st.w; vs *= vs;
    float ra = st.z * st.z;
    float rb = st.y - st.w; rb *= rb;
    float s0 = vs, s1 = st.x, s2 = ra, s3 = rb;
#pragma unroll
    for (int off = 32; off > 0; off >>= 1) {
        s0 += __shfl_xor(s0, off);
        s1 += __shfl_xor(s1, off);
        s2 += __shfl_xor(s2, off);
        s3 += __shfl_xor(s3, off);
    }
    if (b == 0) {
        out[1] = s0; out[2] = s1; out[3] = s2; out[4] = s3;
        out[0] = s0 + s1 + 0.01f * (s2 + s3);
    }
}

extern "C" void kernel_launch(void* const* d_in, const int* in_sizes, int n_in,
                              void* d_out, int out_size, void* d_ws, size_t ws_size,
                              hipStream_t stream) {
    const float* hs  = (const float*)d_in[0];
    const float* w1  = (const float*)d_in[1];
    const float* b1  = (const float*)d_in[2];
    const float* w2  = (const float*)d_in[3];
    const float* b2  = (const float*)d_in[4];
    const float* sw1 = (const float*)d_in[5];
    const float* sb1 = (const float*)d_in[6];
    const float* sw2 = (const float*)d_in[7];
    const float* sb2 = (const float*)d_in[8];
    const float* labels = (const float*)d_in[9];
    const int*   offm   = (const int*)d_in[10];

    float* out = (float*)d_out;
    float* ws  = (float*)d_ws;

    // ws layout (float units) — total footprint 125312 floats (verified size).
    // pooled/zsum ALIAS dead regions:
    //   token_att (ws+0, 32768 f)    : dead after k_mask
    //   w1i       (ws+32768, 43008 f): dead after k_token_att
    float*  token_att = ws;                       // 32768
    __bf16* w1i    = (__bf16*)(ws + 32768);       // 86016 bf16 = 43008 f
    float*  cw     = ws + 32768 + 43008;          // 32768
    short*  cs     = (short*)(cw + 32768);        // 32768 shorts = 16384 f
    int*    nnz    = (int*)(cw + 32768 + 16384);  // 64
    float*  inv    = (float*)(nnz + 64);          // 64
    float4* stats  = (float4*)(inv + 64);         // 64 float4 = 256 f
    float*  pooled = ws;                          // aliases token_att (dead)
    float*  zsum   = ws + 49152;                  // aliases w1i tail (dead)

    // d_out layout: [total, sentence_loss, token_loss, reg_a, reg_b,
    //                masked(64*512), sent(64)]
    float* masked_out = out + 5;
    float* sent_out   = out + 5 + BB * SS;

    hipLaunchKernelGGL(k_prep, dim3(336), dim3(256), 0, stream, w1, w1i);
    hipLaunchKernelGGL(k_token_att, dim3(512), dim3(256), 0, stream,
                       hs, w1i, b1, w2, b2, token_att);
    hipLaunchKernelGGL(k_mask, dim3(BB), dim3(512), 0, stream,
                       token_att, labels, offm, masked_out,
                       cw, cs, nnz, inv, stats);
    hipLaunchKernelGGL(k_pool, dim3(BB, 12), dim3(256), 0, stream,
                       hs, cw, cs, nnz, inv, pooled, zsum);
    hipLaunchKernelGGL(k_sent, dim3(BB, 5), dim3(256), 0, stream,
                       pooled, sw1, sb1, sw2, zsum);
    hipLaunchKernelGGL(k_losses, dim3(1), dim3(64), 0, stream,
                       zsum, sb2, stats, sent_out, out);
}